// Round 7
// baseline (494.215 us; speedup 1.0000x reference)
//
#include <hip/hip_runtime.h>
#include <math.h>

#define N_NODES 100000
#define NPAD 100032         // 1563 * 64, padded row count for 64-row GEMM tiles
#define N_EDGES 1600000
#define EPS 1e-5f
#define NC 64               // edge chunks
#define CHUNK 25000         // N_EDGES / NC
#define NR 98               // ceil(100000/1024) dst ranges
#define RSZ 1024            // nodes per range
#define NRC (NR * NC)       // 6272

typedef __bf16 bf16x8 __attribute__((ext_vector_type(8)));
typedef float f32x4 __attribute__((ext_vector_type(4)));

__device__ inline unsigned short f2bf(float f) {    // RNE, finite inputs
    unsigned u = __float_as_uint(f);
    unsigned r = u + 0x7fffu + ((u >> 16) & 1u);
    return (unsigned short)(r >> 16);
}
__device__ inline float bflo(unsigned u) { return __uint_as_float(u << 16); }
__device__ inline float bfhi(unsigned u) { return __uint_as_float(u & 0xffff0000u); }
__device__ inline unsigned pack2(float lo, float hi) {
    return (unsigned)f2bf(lo) | ((unsigned)f2bf(hi) << 16);
}

// ============ fused prep: x->bf16 cast (blocks 0..12499) + dst-range
// histogram (blocks 12500..12563, chunk = blockIdx-12500) ============
__global__ __launch_bounds__(256) void k_prep(const float* __restrict__ x,
                                              unsigned short* __restrict__ xb,
                                              const int* __restrict__ dst,
                                              int* __restrict__ cntG) {
    __shared__ int hist[NR];
    int t = threadIdx.x;
    if (blockIdx.x < 12500) {
        int idx = blockIdx.x * 256 + t;     // < N_NODES*32 float4
        float4 v = ((const float4*)x)[idx];
        ushort4 o;
        o.x = f2bf(v.x); o.y = f2bf(v.y); o.z = f2bf(v.z); o.w = f2bf(v.w);
        ((ushort4*)xb)[idx] = o;
    } else {
        int c = blockIdx.x - 12500;
        for (int i = t; i < NR; i += 256) hist[i] = 0;
        __syncthreads();
        int base = c * CHUNK;
        for (int i = base + t; i < base + CHUNK; i += 256)
            atomicAdd(&hist[dst[i] >> 10], 1);
        __syncthreads();
        for (int i = t; i < NR; i += 256) cntG[i * NC + c] = hist[i];
    }
}

// ============ fused weight prep ============
// blocks [0,128): WT0; [128,256): WT1; [256,320): WT2
__global__ __launch_bounds__(256) void k_prepw_all(
        const float* __restrict__ Wr0, const float* __restrict__ Wn0,
        const float* __restrict__ Wr1, const float* __restrict__ Wn1,
        const float* __restrict__ Wr2, const float* __restrict__ Wn2,
        unsigned short* __restrict__ WT0, unsigned short* __restrict__ WT1,
        unsigned short* __restrict__ WT2) {
    int b = blockIdx.x, t = threadIdx.x;
    if (b < 256) {
        const float* Wr = (b < 128) ? Wr0 : Wr1;
        const float* Wn = (b < 128) ? Wn0 : Wn1;
        unsigned short* WT = (b < 128) ? WT0 : WT1;
        int idx = (b & 127) * 256 + t;      // < 128*256
        int n = idx >> 8;
        int kc = idx & 255;
        float v = (kc < 128) ? Wr[kc * 128 + n] : Wn[(kc - 128) * 128 + n];
        WT[idx] = f2bf(v);
    } else {
        int idx = (b - 256) * 256 + t;      // < 128*128
        int n = idx >> 7;
        int k = idx & 127;
        float v = (n < 64) ? Wr2[k * 64 + n] : Wn2[k * 64 + (n - 64)];
        WT2[n * 128 + k] = f2bf(v);
    }
}

// ============ exclusive scan of cntG (range-major), 1 block ============
__global__ __launch_bounds__(256) void k_scanA(int* __restrict__ cntG) {
    __shared__ int ts[256];
    int t = threadIdx.x;
    const int PER = 25;                 // 256*25 >= 6272
    int s = 0;
    for (int i = 0; i < PER; ++i) {
        int idx = t * PER + i;
        if (idx < NRC) s += cntG[idx];
    }
    ts[t] = s;
    __syncthreads();
    #pragma unroll
    for (int off = 1; off < 256; off <<= 1) {
        int y = 0;
        if (t >= off) y = ts[t - off];
        __syncthreads();
        if (t >= off) ts[t] += y;
        __syncthreads();
    }
    int run = ts[t] - s;                // exclusive
    for (int i = 0; i < PER; ++i) {
        int idx = t * PER + i;
        if (idx < NRC) {
            int v = cntG[idx];
            cntG[idx] = run;
            run += v;
        }
    }
}

// ============ bin edges by dst-range (LDS cursors) ============
__global__ __launch_bounds__(256) void k_bin(const int* __restrict__ src,
                                             const int* __restrict__ dst,
                                             const int* __restrict__ baseG,
                                             int* __restrict__ bsrc,
                                             int* __restrict__ bdst) {
    __shared__ int cur[NR];
    int t = threadIdx.x, c = blockIdx.x;
    for (int i = t; i < NR; i += 256) cur[i] = baseG[i * NC + c];
    __syncthreads();
    int base = c * CHUNK;
    for (int i = base + t; i < base + CHUNK; i += 256) {
        int d = dst[i];
        int s = src[i];
        int p = atomicAdd(&cur[d >> 10], 1);
        bsrc[p] = s;
        bdst[p] = d;
    }
}

// ============ per-range node histogram -> deg/invdeg + GLOBAL rowptr ====
// Range r's edge segment starts at baseG[r*NC], so rowptr = segment base +
// local exclusive scan. No separate global scan needed.
__global__ __launch_bounds__(256) void k_nodec(const int* __restrict__ bdst,
                                               const int* __restrict__ baseG,
                                               int* __restrict__ deg,
                                               float* __restrict__ invdeg,
                                               int* __restrict__ rowptr) {
    __shared__ int hist[RSZ];
    __shared__ int ps[256];
    int r = blockIdx.x, t = threadIdx.x;
    for (int i = t; i < RSZ; i += 256) hist[i] = 0;
    __syncthreads();
    int s0 = baseG[r * NC];
    int s1 = (r == NR - 1) ? N_EDGES : baseG[(r + 1) * NC];
    int nbase = r << 10;
    for (int i = s0 + t; i < s1; i += 256)
        atomicAdd(&hist[bdst[i] - nbase], 1);
    __syncthreads();
    int h0 = hist[4 * t], h1 = hist[4 * t + 1], h2 = hist[4 * t + 2], h3 = hist[4 * t + 3];
    int tsum = h0 + h1 + h2 + h3;
    ps[t] = tsum;
    __syncthreads();
    #pragma unroll
    for (int off = 1; off < 256; off <<= 1) {
        int y = 0;
        if (t >= off) y = ps[t - off];
        __syncthreads();
        if (t >= off) ps[t] += y;
        __syncthreads();
    }
    int p = s0 + ps[t] - tsum;          // global exclusive position
    int n = nbase + 4 * t;
    int d[4] = {h0, h1, h2, h3};
    #pragma unroll
    for (int k = 0; k < 4; ++k) {
        if (n + k < N_NODES) {
            rowptr[n + k] = p;
            deg[n + k] = d[k];
            invdeg[n + k] = 1.0f / fmaxf((float)d[k], 1.0f);
        }
        p += d[k];
    }
}

// ============ place srcs at rowptr positions (LDS cursor) ============
__global__ __launch_bounds__(256) void k_place(const int* __restrict__ bsrc,
                                               const int* __restrict__ bdst,
                                               const int* __restrict__ baseG,
                                               const int* __restrict__ rowptr,
                                               int* __restrict__ eidx) {
    __shared__ int cur[RSZ];
    int r = blockIdx.x, t = threadIdx.x;
    int nbase = r << 10;
    for (int i = t; i < RSZ; i += 256)
        cur[i] = (nbase + i < N_NODES) ? rowptr[nbase + i] : 0;
    __syncthreads();
    int s0 = baseG[r * NC];
    int s1 = (r == NR - 1) ? N_EDGES : baseG[(r + 1) * NC];
    for (int i = s0 + t; i < s1; i += 256) {
        int d = bdst[i];
        int s = bsrc[i];
        int p = atomicAdd(&cur[d - nbase], 1);
        eidx[p] = s;
    }
}

// ---------------- gather mean-aggregation (bf16, 128-dim) ------------------
// One wave per node; row = 256B = 16 lanes x uint4; sub = lane>>4 picks the
// edge. Main loop: 16 edges, 4 loads in flight. 4-way reduce (xor 16,32).
__global__ __launch_bounds__(256) void k_gather(const uint4* __restrict__ hw4,
                                                const int* __restrict__ eidx,
                                                const int* __restrict__ rowptr,
                                                const int* __restrict__ deg,
                                                const float* __restrict__ invdeg,
                                                uint4* __restrict__ aggw4) {
    int node = blockIdx.x * 4 + (threadIdx.x >> 6);
    int lane = threadIdx.x & 63;
    int sub = lane >> 4;
    int l = lane & 15;
    int start = rowptr[node];
    int cnt = deg[node];
    float a[8];
    #pragma unroll
    for (int i = 0; i < 8; ++i) a[i] = 0.0f;

    int j = 0;
    for (; j + 16 <= cnt; j += 16) {
        int s0 = eidx[start + j + sub];
        int s1 = eidx[start + j + 4 + sub];
        int s2 = eidx[start + j + 8 + sub];
        int s3 = eidx[start + j + 12 + sub];
        uint4 u0 = hw4[(size_t)s0 * 16 + l];
        uint4 u1 = hw4[(size_t)s1 * 16 + l];
        uint4 u2 = hw4[(size_t)s2 * 16 + l];
        uint4 u3 = hw4[(size_t)s3 * 16 + l];
        a[0] += bflo(u0.x) + bflo(u1.x) + bflo(u2.x) + bflo(u3.x);
        a[1] += bfhi(u0.x) + bfhi(u1.x) + bfhi(u2.x) + bfhi(u3.x);
        a[2] += bflo(u0.y) + bflo(u1.y) + bflo(u2.y) + bflo(u3.y);
        a[3] += bfhi(u0.y) + bfhi(u1.y) + bfhi(u2.y) + bfhi(u3.y);
        a[4] += bflo(u0.z) + bflo(u1.z) + bflo(u2.z) + bflo(u3.z);
        a[5] += bfhi(u0.z) + bfhi(u1.z) + bfhi(u2.z) + bfhi(u3.z);
        a[6] += bflo(u0.w) + bflo(u1.w) + bflo(u2.w) + bflo(u3.w);
        a[7] += bfhi(u0.w) + bfhi(u1.w) + bfhi(u2.w) + bfhi(u3.w);
    }
    if (j + 8 <= cnt) {
        int s0 = eidx[start + j + sub];
        int s1 = eidx[start + j + 4 + sub];
        uint4 u0 = hw4[(size_t)s0 * 16 + l];
        uint4 u1 = hw4[(size_t)s1 * 16 + l];
        a[0] += bflo(u0.x) + bflo(u1.x); a[1] += bfhi(u0.x) + bfhi(u1.x);
        a[2] += bflo(u0.y) + bflo(u1.y); a[3] += bfhi(u0.y) + bfhi(u1.y);
        a[4] += bflo(u0.z) + bflo(u1.z); a[5] += bfhi(u0.z) + bfhi(u1.z);
        a[6] += bflo(u0.w) + bflo(u1.w); a[7] += bfhi(u0.w) + bfhi(u1.w);
        j += 8;
    }
    if (j + 4 <= cnt) {
        int s0 = eidx[start + j + sub];
        uint4 u0 = hw4[(size_t)s0 * 16 + l];
        a[0] += bflo(u0.x); a[1] += bfhi(u0.x);
        a[2] += bflo(u0.y); a[3] += bfhi(u0.y);
        a[4] += bflo(u0.z); a[5] += bfhi(u0.z);
        a[6] += bflo(u0.w); a[7] += bfhi(u0.w);
        j += 4;
    }
    int rem = cnt - j;
    if (sub < rem) {
        uint4 u0 = hw4[(size_t)eidx[start + j + sub] * 16 + l];
        a[0] += bflo(u0.x); a[1] += bfhi(u0.x);
        a[2] += bflo(u0.y); a[3] += bfhi(u0.y);
        a[4] += bflo(u0.z); a[5] += bfhi(u0.z);
        a[6] += bflo(u0.w); a[7] += bfhi(u0.w);
    }
    #pragma unroll
    for (int i = 0; i < 8; ++i) {
        a[i] += __shfl_xor(a[i], 16);
        a[i] += __shfl_xor(a[i], 32);
    }
    if (lane < 16) {
        float id = invdeg[node];
        uint4 o;
        o.x = pack2(a[0] * id, a[1] * id);
        o.y = pack2(a[2] * id, a[3] * id);
        o.z = pack2(a[4] * id, a[5] * id);
        o.w = pack2(a[6] * id, a[7] * id);
        aggw4[(size_t)node * 16 + l] = o;
    }
}

// ------ MFMA dual-GEMM + bias + LayerNorm + ReLU (K=256 -> 128), 64 rows ---
// Block 512 thr = 8 waves. Wave w: rows rt*16..+16 (rt=w>>1 in 0..3),
// cols ch*64..+64 (ch=w&1).
__global__ __launch_bounds__(512) void k_gemm_ln(
        const unsigned short* __restrict__ hb, const unsigned short* __restrict__ ab,
        const unsigned short* __restrict__ WT,
        const float* __restrict__ b, const float* __restrict__ g,
        const float* __restrict__ be, unsigned short* __restrict__ outb) {
    __shared__ unsigned short hl[64][136];
    __shared__ unsigned short al[64][136];
    __shared__ unsigned short bt[128][72];
    __shared__ float p1[2][64], p2[2][64];

    const int tid = threadIdx.x;
    const int lane = tid & 63;
    const int w = tid >> 6;
    const int quad = lane >> 4;
    const int l15 = lane & 15;
    const int rt = w >> 1;
    const int ch = w & 1;
    const int row0 = blockIdx.x * 64;

    #pragma unroll
    for (int t = 0; t < 2; ++t) {
        int idx = tid + t * 512;
        int r = idx >> 4;
        int c8 = idx & 15;
        *(float4*)&hl[r][c8 * 8] = ((const float4*)hb)[(size_t)(row0 + r) * 16 + c8];
        *(float4*)&al[r][c8 * 8] = ((const float4*)ab)[(size_t)(row0 + r) * 16 + c8];
    }

    f32x4 acc[4];
    #pragma unroll
    for (int t = 0; t < 4; ++t)
        #pragma unroll
        for (int r = 0; r < 4; ++r) acc[t][r] = 0.0f;

    #pragma unroll
    for (int kt = 0; kt < 4; ++kt) {
        __syncthreads();
        #pragma unroll
        for (int t = 0; t < 2; ++t) {
            int idx = tid + t * 512;
            int n = idx >> 3;
            int c8 = idx & 7;
            *(float4*)&bt[n][c8 * 8] = ((const float4*)WT)[n * 32 + kt * 8 + c8];
        }
        __syncthreads();
        #pragma unroll
        for (int ks = 0; ks < 2; ++ks) {
            const int ck = kt * 64 + ks * 32;
            const unsigned short* ap = (ck < 128)
                ? &hl[rt * 16 + l15][ck + quad * 8]
                : &al[rt * 16 + l15][ck - 128 + quad * 8];
            bf16x8 a = *(const bf16x8*)ap;
            #pragma unroll
            for (int t = 0; t < 4; ++t) {
                bf16x8 bb = *(const bf16x8*)&bt[ch * 64 + t * 16 + l15][ks * 32 + quad * 8];
                acc[t] = __builtin_amdgcn_mfma_f32_16x16x32_bf16(a, bb, acc[t], 0, 0, 0);
            }
        }
    }

    float bcol[4], gc[4], bec[4];
    #pragma unroll
    for (int t = 0; t < 4; ++t) {
        int col = ch * 64 + t * 16 + l15;
        bcol[t] = b[col]; gc[t] = g[col]; bec[t] = be[col];
    }
    float v[4][4];
    float s1[4], s2[4];
    #pragma unroll
    for (int r = 0; r < 4; ++r) { s1[r] = 0.0f; s2[r] = 0.0f; }
    #pragma unroll
    for (int t = 0; t < 4; ++t)
        #pragma unroll
        for (int r = 0; r < 4; ++r) {
            float x = acc[t][r] + bcol[t];
            v[t][r] = x;
            s1[r] += x;
            s2[r] += x * x;
        }
    #pragma unroll
    for (int m = 1; m <= 8; m <<= 1)
        #pragma unroll
        for (int r = 0; r < 4; ++r) {
            s1[r] += __shfl_xor(s1[r], m);
            s2[r] += __shfl_xor(s2[r], m);
        }
    if (l15 == 0) {
        #pragma unroll
        for (int r = 0; r < 4; ++r) {
            int rl = rt * 16 + quad * 4 + r;
            p1[ch][rl] = s1[r];
            p2[ch][rl] = s2[r];
        }
    }
    __syncthreads();
    #pragma unroll
    for (int r = 0; r < 4; ++r) {
        int rl = rt * 16 + quad * 4 + r;
        float S1 = p1[0][rl] + p1[1][rl];
        float S2 = p2[0][rl] + p2[1][rl];
        float mean = S1 * (1.0f / 128.0f);
        float var = S2 * (1.0f / 128.0f) - mean * mean;
        float rstd = rsqrtf(var + EPS);
        #pragma unroll
        for (int t = 0; t < 4; ++t) {
            float o = fmaxf((v[t][r] - mean) * rstd * gc[t] + bec[t], 0.0f);
            outb[(size_t)(row0 + rl) * 128 + ch * 64 + t * 16 + l15] = f2bf(o);
        }
    }
}

// ------ layer 2 GEMM: zy = h2 @ [Wr2|Wn2] (+b2 on z half), 64 rows ---------
__global__ __launch_bounds__(512) void k_gemm2(
        const unsigned short* __restrict__ hb, const unsigned short* __restrict__ WT,
        const float* __restrict__ b2, unsigned short* __restrict__ zyb) {
    __shared__ unsigned short hl[64][136];
    __shared__ unsigned short bt[128][136];

    const int tid = threadIdx.x;
    const int lane = tid & 63;
    const int w = tid >> 6;
    const int quad = lane >> 4;
    const int l15 = lane & 15;
    const int rt = w >> 1;
    const int ch = w & 1;
    const int row0 = blockIdx.x * 64;

    #pragma unroll
    for (int t = 0; t < 2; ++t) {
        int idx = tid + t * 512;
        int r = idx >> 4;
        int c8 = idx & 15;
        *(float4*)&hl[r][c8 * 8] = ((const float4*)hb)[(size_t)(row0 + r) * 16 + c8];
    }
    #pragma unroll
    for (int t = 0; t < 4; ++t) {
        int idx = tid + t * 512;
        int n = idx >> 4;
        int c8 = idx & 15;
        *(float4*)&bt[n][c8 * 8] = ((const float4*)WT)[n * 16 + c8];
    }
    __syncthreads();

    f32x4 acc[4];
    #pragma unroll
    for (int t = 0; t < 4; ++t)
        #pragma unroll
        for (int r = 0; r < 4; ++r) acc[t][r] = 0.0f;

    #pragma unroll
    for (int ks = 0; ks < 4; ++ks) {
        bf16x8 a = *(const bf16x8*)&hl[rt * 16 + l15][ks * 32 + quad * 8];
        #pragma unroll
        for (int t = 0; t < 4; ++t) {
            bf16x8 bb = *(const bf16x8*)&bt[ch * 64 + t * 16 + l15][ks * 32 + quad * 8];
            acc[t] = __builtin_amdgcn_mfma_f32_16x16x32_bf16(a, bb, acc[t], 0, 0, 0);
        }
    }

    #pragma unroll
    for (int t = 0; t < 4; ++t) {
        int col = ch * 64 + t * 16 + l15;
        float bc = (col < 64) ? b2[col] : 0.0f;
        #pragma unroll
        for (int r = 0; r < 4; ++r) {
            int rl = rt * 16 + quad * 4 + r;
            zyb[(size_t)(row0 + rl) * 128 + col] = f2bf(acc[t][r] + bc);
        }
    }
}

// ------- final: gather-mean y (64-dim) + z + log_softmax, fp32 out ---------
__global__ __launch_bounds__(256) void k_l2g(const uint4* __restrict__ zy4,
                                             const int* __restrict__ eidx,
                                             const int* __restrict__ rowptr,
                                             const int* __restrict__ deg,
                                             const float* __restrict__ invdeg,
                                             float* __restrict__ out) {
    int node = blockIdx.x * 8 + (threadIdx.x >> 5);
    int lane = threadIdx.x & 31;
    int sub = lane >> 3;
    int l = lane & 7;
    int start = rowptr[node];
    int cnt = deg[node];
    float a[8];
    #pragma unroll
    for (int i = 0; i < 8; ++i) a[i] = 0.0f;

    int j = 0;
    for (; j + 16 <= cnt; j += 16) {
        int s0 = eidx[start + j + sub];
        int s1 = eidx[start + j + 4 + sub];
        int s2 = eidx[start + j + 8 + sub];
        int s3 = eidx[start + j + 12 + sub];
        uint4 u0 = zy4[(size_t)s0 * 16 + 8 + l];
        uint4 u1 = zy4[(size_t)s1 * 16 + 8 + l];
        uint4 u2 = zy4[(size_t)s2 * 16 + 8 + l];
        uint4 u3 = zy4[(size_t)s3 * 16 + 8 + l];
        a[0] += bflo(u0.x) + bflo(u1.x) + bflo(u2.x) + bflo(u3.x);
        a[1] += bfhi(u0.x) + bfhi(u1.x) + bfhi(u2.x) + bfhi(u3.x);
        a[2] += bflo(u0.y) + bflo(u1.y) + bflo(u2.y) + bflo(u3.y);
        a[3] += bfhi(u0.y) + bfhi(u1.y) + bfhi(u2.y) + bfhi(u3.y);
        a[4] += bflo(u0.z) + bflo(u1.z) + bflo(u2.z) + bflo(u3.z);
        a[5] += bfhi(u0.z) + bfhi(u1.z) + bfhi(u2.z) + bfhi(u3.z);
        a[6] += bflo(u0.w) + bflo(u1.w) + bflo(u2.w) + bflo(u3.w);
        a[7] += bfhi(u0.w) + bfhi(u1.w) + bfhi(u2.w) + bfhi(u3.w);
    }
    if (j + 8 <= cnt) {
        int s0 = eidx[start + j + sub];
        int s1 = eidx[start + j + 4 + sub];
        uint4 u0 = zy4[(size_t)s0 * 16 + 8 + l];
        uint4 u1 = zy4[(size_t)s1 * 16 + 8 + l];
        a[0] += bflo(u0.x) + bflo(u1.x); a[1] += bfhi(u0.x) + bfhi(u1.x);
        a[2] += bflo(u0.y) + bflo(u1.y); a[3] += bfhi(u0.y) + bfhi(u1.y);
        a[4] += bflo(u0.z) + bflo(u1.z); a[5] += bfhi(u0.z) + bfhi(u1.z);
        a[6] += bflo(u0.w) + bflo(u1.w); a[7] += bfhi(u0.w) + bfhi(u1.w);
        j += 8;
    }
    if (j + 4 <= cnt) {
        int s0 = eidx[start + j + sub];
        uint4 u0 = zy4[(size_t)s0 * 16 + 8 + l];
        a[0] += bflo(u0.x); a[1] += bfhi(u0.x);
        a[2] += bflo(u0.y); a[3] += bfhi(u0.y);
        a[4] += bflo(u0.z); a[5] += bfhi(u0.z);
        a[6] += bflo(u0.w); a[7] += bfhi(u0.w);
        j += 4;
    }
    int rem = cnt - j;
    if (sub < rem) {
        uint4 u0 = zy4[(size_t)eidx[start + j + sub] * 16 + 8 + l];
        a[0] += bflo(u0.x); a[1] += bfhi(u0.x);
        a[2] += bflo(u0.y); a[3] += bfhi(u0.y);
        a[4] += bflo(u0.z); a[5] += bfhi(u0.z);
        a[6] += bflo(u0.w); a[7] += bfhi(u0.w);
    }
    #pragma unroll
    for (int i = 0; i < 8; ++i) {
        a[i] += __shfl_xor(a[i], 8);
        a[i] += __shfl_xor(a[i], 16);
    }

    float id = invdeg[node];
    uint4 uz = zy4[(size_t)node * 16 + l];
    float v[8];
    v[0] = bflo(uz.x) + a[0] * id; v[1] = bfhi(uz.x) + a[1] * id;
    v[2] = bflo(uz.y) + a[2] * id; v[3] = bfhi(uz.y) + a[3] * id;
    v[4] = bflo(uz.z) + a[4] * id; v[5] = bfhi(uz.z) + a[5] * id;
    v[6] = bflo(uz.w) + a[6] * id; v[7] = bfhi(uz.w) + a[7] * id;

    float m = v[0];
    #pragma unroll
    for (int i = 1; i < 8; ++i) m = fmaxf(m, v[i]);
    #pragma unroll
    for (int msk = 1; msk <= 4; msk <<= 1) m = fmaxf(m, __shfl_xor(m, msk));
    float s = 0.0f;
    #pragma unroll
    for (int i = 0; i < 8; ++i) s += __expf(v[i] - m);
    #pragma unroll
    for (int msk = 1; msk <= 4; msk <<= 1) s += __shfl_xor(s, msk);
    if (sub == 0) {
        float L = m + logf(s);
        float4 o0, o1;
        o0.x = v[0] - L; o0.y = v[1] - L; o0.z = v[2] - L; o0.w = v[3] - L;
        o1.x = v[4] - L; o1.y = v[5] - L; o1.z = v[6] - L; o1.w = v[7] - L;
        ((float4*)out)[(size_t)node * 16 + l * 2] = o0;
        ((float4*)out)[(size_t)node * 16 + l * 2 + 1] = o1;
    }
}

extern "C" void kernel_launch(void* const* d_in, const int* in_sizes, int n_in,
                              void* d_out, int out_size, void* d_ws, size_t ws_size,
                              hipStream_t stream) {
    const float* x   = (const float*)d_in[0];
    const int* esrc  = (const int*)d_in[1];
    const int* edst  = (const int*)d_in[2];
    const float* Wr0 = (const float*)d_in[3];
    const float* Wn0 = (const float*)d_in[4];
    const float* b0  = (const float*)d_in[5];
    const float* g0  = (const float*)d_in[6];
    const float* be0 = (const float*)d_in[7];
    const float* Wr1 = (const float*)d_in[8];
    const float* Wn1 = (const float*)d_in[9];
    const float* b1  = (const float*)d_in[10];
    const float* g1  = (const float*)d_in[11];
    const float* be1 = (const float*)d_in[12];
    const float* Wr2 = (const float*)d_in[13];
    const float* Wn2 = (const float*)d_in[14];
    const float* b2  = (const float*)d_in[15];
    float* out = (float*)d_out;

    char* p = (char*)d_ws;
    auto alloc = [&](size_t bytes) {
        void* r = (void*)p;
        p += (bytes + 255) & ~(size_t)255;
        return r;
    };
    int*   deg    = (int*)  alloc(N_NODES * 4);
    float* invdeg = (float*)alloc(N_NODES * 4);
    int*   rowptr = (int*)  alloc(N_NODES * 4);
    int*   cntG   = (int*)  alloc(NRC * 4);
    int*   bsrc   = (int*)  alloc((size_t)N_EDGES * 4);
    int*   bdst   = (int*)  alloc((size_t)N_EDGES * 4);
    int*   eidx   = (int*)  alloc((size_t)N_EDGES * 4);
    unsigned short* xb   = (unsigned short*)alloc((size_t)NPAD * 128 * 2); // also h2
    unsigned short* h1   = (unsigned short*)alloc((size_t)NPAD * 128 * 2); // also zy
    unsigned short* aggb = (unsigned short*)alloc((size_t)NPAD * 128 * 2);
    unsigned short* WT0  = (unsigned short*)alloc(128 * 256 * 2);
    unsigned short* WT1  = (unsigned short*)alloc(128 * 256 * 2);
    unsigned short* WT2  = (unsigned short*)alloc(128 * 128 * 2);

    // prep (cast + dst-range count) and weight transpose
    k_prep<<<12500 + NC, 256, 0, stream>>>(x, xb, edst, cntG);
    k_prepw_all<<<320, 256, 0, stream>>>(Wr0, Wn0, Wr1, Wn1, Wr2, Wn2, WT0, WT1, WT2);

    // CSR build
    k_scanA<<<1, 256, 0, stream>>>(cntG);
    k_bin<<<NC, 256, 0, stream>>>(esrc, edst, cntG, bsrc, bdst);
    k_nodec<<<NR, 256, 0, stream>>>(bdst, cntG, deg, invdeg, rowptr);
    k_place<<<NR, 256, 0, stream>>>(bsrc, bdst, cntG, rowptr, eidx);

    // layer 0
    k_gather<<<N_NODES / 4, 256, 0, stream>>>((const uint4*)xb, eidx, rowptr, deg, invdeg, (uint4*)aggb);
    k_gemm_ln<<<NPAD / 64, 512, 0, stream>>>(xb, aggb, WT0, b0, g0, be0, h1);

    // layer 1 (h2 goes back into xb's buffer)
    k_gather<<<N_NODES / 4, 256, 0, stream>>>((const uint4*)h1, eidx, rowptr, deg, invdeg, (uint4*)aggb);
    k_gemm_ln<<<NPAD / 64, 512, 0, stream>>>(h1, aggb, WT1, b1, g1, be1, xb);

    // layer 2: zy = h2 @ [Wr2|Wn2] (+b2), then gather y-half + log_softmax
    k_gemm2<<<NPAD / 64, 512, 0, stream>>>(xb, WT2, b2, h1);
    k_l2g<<<N_NODES / 8, 256, 0, stream>>>((const uint4*)h1, eidx, rowptr, deg, invdeg, out);
}

// Round 8
// 433.190 us; speedup vs baseline: 1.1409x; 1.1409x over previous
//
#include <hip/hip_runtime.h>
#include <math.h>

#define N_NODES 100000
#define NPAD 100032         // 1563 * 64, padded row count for 64-row GEMM tiles
#define N_EDGES 1600000
#define EPS 1e-5f
#define NC 256              // edge chunks (256 blocks -> parallelism; R7's NC=64 was a 2%-occupancy regression)
#define CHUNK 6250          // N_EDGES / NC
#define NR 98               // ceil(100000/1024) dst ranges
#define RSZ 1024            // nodes per range
#define NRC (NR * NC)       // 25088

typedef __bf16 bf16x8 __attribute__((ext_vector_type(8)));
typedef float f32x4 __attribute__((ext_vector_type(4)));

__device__ inline unsigned short f2bf(float f) {    // RNE, finite inputs
    unsigned u = __float_as_uint(f);
    unsigned r = u + 0x7fffu + ((u >> 16) & 1u);
    return (unsigned short)(r >> 16);
}
__device__ inline float bflo(unsigned u) { return __uint_as_float(u << 16); }
__device__ inline float bfhi(unsigned u) { return __uint_as_float(u & 0xffff0000u); }
__device__ inline unsigned pack2(float lo, float hi) {
    return (unsigned)f2bf(lo) | ((unsigned)f2bf(hi) << 16);
}

// ============ fused prep: x->bf16 cast (blocks 0..12499) + dst-range
// histogram (blocks 12500..12755, chunk = blockIdx-12500) ============
__global__ __launch_bounds__(256) void k_prep(const float* __restrict__ x,
                                              unsigned short* __restrict__ xb,
                                              const int* __restrict__ dst,
                                              int* __restrict__ cntG) {
    __shared__ int hist[NR];
    int t = threadIdx.x;
    if (blockIdx.x < 12500) {
        int idx = blockIdx.x * 256 + t;     // < N_NODES*32 float4
        float4 v = ((const float4*)x)[idx];
        ushort4 o;
        o.x = f2bf(v.x); o.y = f2bf(v.y); o.z = f2bf(v.z); o.w = f2bf(v.w);
        ((ushort4*)xb)[idx] = o;
    } else {
        int c = blockIdx.x - 12500;
        for (int i = t; i < NR; i += 256) hist[i] = 0;
        __syncthreads();
        int base = c * CHUNK;
        for (int i = base + t; i < base + CHUNK; i += 256)
            atomicAdd(&hist[dst[i] >> 10], 1);
        __syncthreads();
        for (int i = t; i < NR; i += 256) cntG[i * NC + c] = hist[i];
    }
}

// ============ fused weight prep ============
// blocks [0,128): WT0; [128,256): WT1; [256,320): WT2
__global__ __launch_bounds__(256) void k_prepw_all(
        const float* __restrict__ Wr0, const float* __restrict__ Wn0,
        const float* __restrict__ Wr1, const float* __restrict__ Wn1,
        const float* __restrict__ Wr2, const float* __restrict__ Wn2,
        unsigned short* __restrict__ WT0, unsigned short* __restrict__ WT1,
        unsigned short* __restrict__ WT2) {
    int b = blockIdx.x, t = threadIdx.x;
    if (b < 256) {
        const float* Wr = (b < 128) ? Wr0 : Wr1;
        const float* Wn = (b < 128) ? Wn0 : Wn1;
        unsigned short* WT = (b < 128) ? WT0 : WT1;
        int idx = (b & 127) * 256 + t;      // < 128*256
        int n = idx >> 8;
        int kc = idx & 255;
        float v = (kc < 128) ? Wr[kc * 128 + n] : Wn[(kc - 128) * 128 + n];
        WT[idx] = f2bf(v);
    } else {
        int idx = (b - 256) * 256 + t;      // < 128*128
        int n = idx >> 7;
        int k = idx & 127;
        float v = (n < 64) ? Wr2[k * 64 + n] : Wn2[k * 64 + (n - 64)];
        WT2[n * 128 + k] = f2bf(v);
    }
}

// ============ exclusive scan of cntG (range-major), 1 block ============
__global__ __launch_bounds__(256) void k_scanA(int* __restrict__ cntG) {
    __shared__ int ts[256];
    int t = threadIdx.x;
    const int PER = NRC / 256;          // 98
    int s = 0;
    for (int i = 0; i < PER; ++i) s += cntG[t * PER + i];
    ts[t] = s;
    __syncthreads();
    #pragma unroll
    for (int off = 1; off < 256; off <<= 1) {
        int y = 0;
        if (t >= off) y = ts[t - off];
        __syncthreads();
        if (t >= off) ts[t] += y;
        __syncthreads();
    }
    int run = ts[t] - s;                // exclusive
    for (int i = 0; i < PER; ++i) {
        int v = cntG[t * PER + i];
        cntG[t * PER + i] = run;
        run += v;
    }
}

// ============ bin edges by dst-range (LDS cursors), 256 blocks ============
__global__ __launch_bounds__(256) void k_bin(const int* __restrict__ src,
                                             const int* __restrict__ dst,
                                             const int* __restrict__ baseG,
                                             int* __restrict__ bsrc,
                                             int* __restrict__ bdst) {
    __shared__ int cur[NR];
    int t = threadIdx.x, c = blockIdx.x;
    for (int i = t; i < NR; i += 256) cur[i] = baseG[i * NC + c];
    __syncthreads();
    int base = c * CHUNK;
    for (int i = base + t; i < base + CHUNK; i += 256) {
        int d = dst[i];
        int s = src[i];
        int p = atomicAdd(&cur[d >> 10], 1);
        bsrc[p] = s;
        bdst[p] = d;
    }
}

// ============ fused per-range: histogram -> deg/invdeg/rowptr -> place =====
// Range r's edge segment starts at baseG[r*NC]; rowptr = segment base +
// local exclusive scan. Then place srcs via LDS cursors (segment is L2-hot).
__global__ __launch_bounds__(256) void k_nodeplace(
        const int* __restrict__ bsrc, const int* __restrict__ bdst,
        const int* __restrict__ baseG,
        int* __restrict__ deg, float* __restrict__ invdeg,
        int* __restrict__ rowptr, int* __restrict__ eidx) {
    __shared__ int hist[RSZ];
    __shared__ int cur[RSZ];
    __shared__ int ps[256];
    int r = blockIdx.x, t = threadIdx.x;
    for (int i = t; i < RSZ; i += 256) hist[i] = 0;
    __syncthreads();
    int s0 = baseG[r * NC];
    int s1 = (r == NR - 1) ? N_EDGES : baseG[(r + 1) * NC];
    int nbase = r << 10;
    for (int i = s0 + t; i < s1; i += 256)
        atomicAdd(&hist[bdst[i] - nbase], 1);
    __syncthreads();
    int h0 = hist[4 * t], h1 = hist[4 * t + 1], h2 = hist[4 * t + 2], h3 = hist[4 * t + 3];
    int tsum = h0 + h1 + h2 + h3;
    ps[t] = tsum;
    __syncthreads();
    #pragma unroll
    for (int off = 1; off < 256; off <<= 1) {
        int y = 0;
        if (t >= off) y = ps[t - off];
        __syncthreads();
        if (t >= off) ps[t] += y;
        __syncthreads();
    }
    int p = s0 + ps[t] - tsum;          // global exclusive position
    int n = nbase + 4 * t;
    int d[4] = {h0, h1, h2, h3};
    #pragma unroll
    for (int k = 0; k < 4; ++k) {
        cur[4 * t + k] = p;
        if (n + k < N_NODES) {
            rowptr[n + k] = p;
            deg[n + k] = d[k];
            invdeg[n + k] = 1.0f / fmaxf((float)d[k], 1.0f);
        }
        p += d[k];
    }
    __syncthreads();
    for (int i = s0 + t; i < s1; i += 256) {
        int dd = bdst[i];
        int s = bsrc[i];
        int pp = atomicAdd(&cur[dd - nbase], 1);
        eidx[pp] = s;
    }
}

// ---------------- gather mean-aggregation (bf16, 128-dim) ------------------
// One wave per node; row = 256B = 16 lanes x uint4; sub = lane>>4 picks the
// edge. Main loop: 16 edges, 4 loads in flight. 4-way reduce (xor 16,32).
__global__ __launch_bounds__(256) void k_gather(const uint4* __restrict__ hw4,
                                                const int* __restrict__ eidx,
                                                const int* __restrict__ rowptr,
                                                const int* __restrict__ deg,
                                                const float* __restrict__ invdeg,
                                                uint4* __restrict__ aggw4) {
    int node = blockIdx.x * 4 + (threadIdx.x >> 6);
    int lane = threadIdx.x & 63;
    int sub = lane >> 4;
    int l = lane & 15;
    int start = rowptr[node];
    int cnt = deg[node];
    float a[8];
    #pragma unroll
    for (int i = 0; i < 8; ++i) a[i] = 0.0f;

    int j = 0;
    for (; j + 16 <= cnt; j += 16) {
        int s0 = eidx[start + j + sub];
        int s1 = eidx[start + j + 4 + sub];
        int s2 = eidx[start + j + 8 + sub];
        int s3 = eidx[start + j + 12 + sub];
        uint4 u0 = hw4[(size_t)s0 * 16 + l];
        uint4 u1 = hw4[(size_t)s1 * 16 + l];
        uint4 u2 = hw4[(size_t)s2 * 16 + l];
        uint4 u3 = hw4[(size_t)s3 * 16 + l];
        a[0] += bflo(u0.x) + bflo(u1.x) + bflo(u2.x) + bflo(u3.x);
        a[1] += bfhi(u0.x) + bfhi(u1.x) + bfhi(u2.x) + bfhi(u3.x);
        a[2] += bflo(u0.y) + bflo(u1.y) + bflo(u2.y) + bflo(u3.y);
        a[3] += bfhi(u0.y) + bfhi(u1.y) + bfhi(u2.y) + bfhi(u3.y);
        a[4] += bflo(u0.z) + bflo(u1.z) + bflo(u2.z) + bflo(u3.z);
        a[5] += bfhi(u0.z) + bfhi(u1.z) + bfhi(u2.z) + bfhi(u3.z);
        a[6] += bflo(u0.w) + bflo(u1.w) + bflo(u2.w) + bflo(u3.w);
        a[7] += bfhi(u0.w) + bfhi(u1.w) + bfhi(u2.w) + bfhi(u3.w);
    }
    if (j + 8 <= cnt) {
        int s0 = eidx[start + j + sub];
        int s1 = eidx[start + j + 4 + sub];
        uint4 u0 = hw4[(size_t)s0 * 16 + l];
        uint4 u1 = hw4[(size_t)s1 * 16 + l];
        a[0] += bflo(u0.x) + bflo(u1.x); a[1] += bfhi(u0.x) + bfhi(u1.x);
        a[2] += bflo(u0.y) + bflo(u1.y); a[3] += bfhi(u0.y) + bfhi(u1.y);
        a[4] += bflo(u0.z) + bflo(u1.z); a[5] += bfhi(u0.z) + bfhi(u1.z);
        a[6] += bflo(u0.w) + bflo(u1.w); a[7] += bfhi(u0.w) + bfhi(u1.w);
        j += 8;
    }
    if (j + 4 <= cnt) {
        int s0 = eidx[start + j + sub];
        uint4 u0 = hw4[(size_t)s0 * 16 + l];
        a[0] += bflo(u0.x); a[1] += bfhi(u0.x);
        a[2] += bflo(u0.y); a[3] += bfhi(u0.y);
        a[4] += bflo(u0.z); a[5] += bfhi(u0.z);
        a[6] += bflo(u0.w); a[7] += bfhi(u0.w);
        j += 4;
    }
    int rem = cnt - j;
    if (sub < rem) {
        uint4 u0 = hw4[(size_t)eidx[start + j + sub] * 16 + l];
        a[0] += bflo(u0.x); a[1] += bfhi(u0.x);
        a[2] += bflo(u0.y); a[3] += bfhi(u0.y);
        a[4] += bflo(u0.z); a[5] += bfhi(u0.z);
        a[6] += bflo(u0.w); a[7] += bfhi(u0.w);
    }
    #pragma unroll
    for (int i = 0; i < 8; ++i) {
        a[i] += __shfl_xor(a[i], 16);
        a[i] += __shfl_xor(a[i], 32);
    }
    if (lane < 16) {
        float id = invdeg[node];
        uint4 o;
        o.x = pack2(a[0] * id, a[1] * id);
        o.y = pack2(a[2] * id, a[3] * id);
        o.z = pack2(a[4] * id, a[5] * id);
        o.w = pack2(a[6] * id, a[7] * id);
        aggw4[(size_t)node * 16 + l] = o;
    }
}

// ------ MFMA dual-GEMM + bias + LayerNorm + ReLU (K=256 -> 128), 64 rows ---
__global__ __launch_bounds__(512) void k_gemm_ln(
        const unsigned short* __restrict__ hb, const unsigned short* __restrict__ ab,
        const unsigned short* __restrict__ WT,
        const float* __restrict__ b, const float* __restrict__ g,
        const float* __restrict__ be, unsigned short* __restrict__ outb) {
    __shared__ unsigned short hl[64][136];
    __shared__ unsigned short al[64][136];
    __shared__ unsigned short bt[128][72];
    __shared__ float p1[2][64], p2[2][64];

    const int tid = threadIdx.x;
    const int lane = tid & 63;
    const int w = tid >> 6;
    const int quad = lane >> 4;
    const int l15 = lane & 15;
    const int rt = w >> 1;
    const int ch = w & 1;
    const int row0 = blockIdx.x * 64;

    #pragma unroll
    for (int t = 0; t < 2; ++t) {
        int idx = tid + t * 512;
        int r = idx >> 4;
        int c8 = idx & 15;
        *(float4*)&hl[r][c8 * 8] = ((const float4*)hb)[(size_t)(row0 + r) * 16 + c8];
        *(float4*)&al[r][c8 * 8] = ((const float4*)ab)[(size_t)(row0 + r) * 16 + c8];
    }

    f32x4 acc[4];
    #pragma unroll
    for (int t = 0; t < 4; ++t)
        #pragma unroll
        for (int r = 0; r < 4; ++r) acc[t][r] = 0.0f;

    #pragma unroll
    for (int kt = 0; kt < 4; ++kt) {
        __syncthreads();
        #pragma unroll
        for (int t = 0; t < 2; ++t) {
            int idx = tid + t * 512;
            int n = idx >> 3;
            int c8 = idx & 7;
            *(float4*)&bt[n][c8 * 8] = ((const float4*)WT)[n * 32 + kt * 8 + c8];
        }
        __syncthreads();
        #pragma unroll
        for (int ks = 0; ks < 2; ++ks) {
            const int ck = kt * 64 + ks * 32;
            const unsigned short* ap = (ck < 128)
                ? &hl[rt * 16 + l15][ck + quad * 8]
                : &al[rt * 16 + l15][ck - 128 + quad * 8];
            bf16x8 a = *(const bf16x8*)ap;
            #pragma unroll
            for (int t = 0; t < 4; ++t) {
                bf16x8 bb = *(const bf16x8*)&bt[ch * 64 + t * 16 + l15][ks * 32 + quad * 8];
                acc[t] = __builtin_amdgcn_mfma_f32_16x16x32_bf16(a, bb, acc[t], 0, 0, 0);
            }
        }
    }

    float bcol[4], gc[4], bec[4];
    #pragma unroll
    for (int t = 0; t < 4; ++t) {
        int col = ch * 64 + t * 16 + l15;
        bcol[t] = b[col]; gc[t] = g[col]; bec[t] = be[col];
    }
    float v[4][4];
    float s1[4], s2[4];
    #pragma unroll
    for (int r = 0; r < 4; ++r) { s1[r] = 0.0f; s2[r] = 0.0f; }
    #pragma unroll
    for (int t = 0; t < 4; ++t)
        #pragma unroll
        for (int r = 0; r < 4; ++r) {
            float x = acc[t][r] + bcol[t];
            v[t][r] = x;
            s1[r] += x;
            s2[r] += x * x;
        }
    #pragma unroll
    for (int m = 1; m <= 8; m <<= 1)
        #pragma unroll
        for (int r = 0; r < 4; ++r) {
            s1[r] += __shfl_xor(s1[r], m);
            s2[r] += __shfl_xor(s2[r], m);
        }
    if (l15 == 0) {
        #pragma unroll
        for (int r = 0; r < 4; ++r) {
            int rl = rt * 16 + quad * 4 + r;
            p1[ch][rl] = s1[r];
            p2[ch][rl] = s2[r];
        }
    }
    __syncthreads();
    #pragma unroll
    for (int r = 0; r < 4; ++r) {
        int rl = rt * 16 + quad * 4 + r;
        float S1 = p1[0][rl] + p1[1][rl];
        float S2 = p2[0][rl] + p2[1][rl];
        float mean = S1 * (1.0f / 128.0f);
        float var = S2 * (1.0f / 128.0f) - mean * mean;
        float rstd = rsqrtf(var + EPS);
        #pragma unroll
        for (int t = 0; t < 4; ++t) {
            float o = fmaxf((v[t][r] - mean) * rstd * gc[t] + bec[t], 0.0f);
            outb[(size_t)(row0 + rl) * 128 + ch * 64 + t * 16 + l15] = f2bf(o);
        }
    }
}

// ------ layer 2 GEMM: zy = h2 @ [Wr2|Wn2] (+b2 on z half), 64 rows ---------
__global__ __launch_bounds__(512) void k_gemm2(
        const unsigned short* __restrict__ hb, const unsigned short* __restrict__ WT,
        const float* __restrict__ b2, unsigned short* __restrict__ zyb) {
    __shared__ unsigned short hl[64][136];
    __shared__ unsigned short bt[128][136];

    const int tid = threadIdx.x;
    const int lane = tid & 63;
    const int w = tid >> 6;
    const int quad = lane >> 4;
    const int l15 = lane & 15;
    const int rt = w >> 1;
    const int ch = w & 1;
    const int row0 = blockIdx.x * 64;

    #pragma unroll
    for (int t = 0; t < 2; ++t) {
        int idx = tid + t * 512;
        int r = idx >> 4;
        int c8 = idx & 15;
        *(float4*)&hl[r][c8 * 8] = ((const float4*)hb)[(size_t)(row0 + r) * 16 + c8];
    }
    #pragma unroll
    for (int t = 0; t < 4; ++t) {
        int idx = tid + t * 512;
        int n = idx >> 4;
        int c8 = idx & 15;
        *(float4*)&bt[n][c8 * 8] = ((const float4*)WT)[n * 16 + c8];
    }
    __syncthreads();

    f32x4 acc[4];
    #pragma unroll
    for (int t = 0; t < 4; ++t)
        #pragma unroll
        for (int r = 0; r < 4; ++r) acc[t][r] = 0.0f;

    #pragma unroll
    for (int ks = 0; ks < 4; ++ks) {
        bf16x8 a = *(const bf16x8*)&hl[rt * 16 + l15][ks * 32 + quad * 8];
        #pragma unroll
        for (int t = 0; t < 4; ++t) {
            bf16x8 bb = *(const bf16x8*)&bt[ch * 64 + t * 16 + l15][ks * 32 + quad * 8];
            acc[t] = __builtin_amdgcn_mfma_f32_16x16x32_bf16(a, bb, acc[t], 0, 0, 0);
        }
    }

    #pragma unroll
    for (int t = 0; t < 4; ++t) {
        int col = ch * 64 + t * 16 + l15;
        float bc = (col < 64) ? b2[col] : 0.0f;
        #pragma unroll
        for (int r = 0; r < 4; ++r) {
            int rl = rt * 16 + quad * 4 + r;
            zyb[(size_t)(row0 + rl) * 128 + col] = f2bf(acc[t][r] + bc);
        }
    }
}

// ------- final: gather-mean y (64-dim) + z + log_softmax, fp32 out ---------
__global__ __launch_bounds__(256) void k_l2g(const uint4* __restrict__ zy4,
                                             const int* __restrict__ eidx,
                                             const int* __restrict__ rowptr,
                                             const int* __restrict__ deg,
                                             const float* __restrict__ invdeg,
                                             float* __restrict__ out) {
    int node = blockIdx.x * 8 + (threadIdx.x >> 5);
    int lane = threadIdx.x & 31;
    int sub = lane >> 3;
    int l = lane & 7;
    int start = rowptr[node];
    int cnt = deg[node];
    float a[8];
    #pragma unroll
    for (int i = 0; i < 8; ++i) a[i] = 0.0f;

    int j = 0;
    for (; j + 16 <= cnt; j += 16) {
        int s0 = eidx[start + j + sub];
        int s1 = eidx[start + j + 4 + sub];
        int s2 = eidx[start + j + 8 + sub];
        int s3 = eidx[start + j + 12 + sub];
        uint4 u0 = zy4[(size_t)s0 * 16 + 8 + l];
        uint4 u1 = zy4[(size_t)s1 * 16 + 8 + l];
        uint4 u2 = zy4[(size_t)s2 * 16 + 8 + l];
        uint4 u3 = zy4[(size_t)s3 * 16 + 8 + l];
        a[0] += bflo(u0.x) + bflo(u1.x) + bflo(u2.x) + bflo(u3.x);
        a[1] += bfhi(u0.x) + bfhi(u1.x) + bfhi(u2.x) + bfhi(u3.x);
        a[2] += bflo(u0.y) + bflo(u1.y) + bflo(u2.y) + bflo(u3.y);
        a[3] += bfhi(u0.y) + bfhi(u1.y) + bfhi(u2.y) + bfhi(u3.y);
        a[4] += bflo(u0.z) + bflo(u1.z) + bflo(u2.z) + bflo(u3.z);
        a[5] += bfhi(u0.z) + bfhi(u1.z) + bfhi(u2.z) + bfhi(u3.z);
        a[6] += bflo(u0.w) + bflo(u1.w) + bflo(u2.w) + bflo(u3.w);
        a[7] += bfhi(u0.w) + bfhi(u1.w) + bfhi(u2.w) + bfhi(u3.w);
    }
    if (j + 8 <= cnt) {
        int s0 = eidx[start + j + sub];
        int s1 = eidx[start + j + 4 + sub];
        uint4 u0 = zy4[(size_t)s0 * 16 + 8 + l];
        uint4 u1 = zy4[(size_t)s1 * 16 + 8 + l];
        a[0] += bflo(u0.x) + bflo(u1.x); a[1] += bfhi(u0.x) + bfhi(u1.x);
        a[2] += bflo(u0.y) + bflo(u1.y); a[3] += bfhi(u0.y) + bfhi(u1.y);
        a[4] += bflo(u0.z) + bflo(u1.z); a[5] += bfhi(u0.z) + bfhi(u1.z);
        a[6] += bflo(u0.w) + bflo(u1.w); a[7] += bfhi(u0.w) + bfhi(u1.w);
        j += 8;
    }
    if (j + 4 <= cnt) {
        int s0 = eidx[start + j + sub];
        uint4 u0 = zy4[(size_t)s0 * 16 + 8 + l];
        a[0] += bflo(u0.x); a[1] += bfhi(u0.x);
        a[2] += bflo(u0.y); a[3] += bfhi(u0.y);
        a[4] += bflo(u0.z); a[5] += bfhi(u0.z);
        a[6] += bflo(u0.w); a[7] += bfhi(u0.w);
        j += 4;
    }
    int rem = cnt - j;
    if (sub < rem) {
        uint4 u0 = zy4[(size_t)eidx[start + j + sub] * 16 + 8 + l];
        a[0] += bflo(u0.x); a[1] += bfhi(u0.x);
        a[2] += bflo(u0.y); a[3] += bfhi(u0.y);
        a[4] += bflo(u0.z); a[5] += bfhi(u0.z);
        a[6] += bflo(u0.w); a[7] += bfhi(u0.w);
    }
    #pragma unroll
    for (int i = 0; i < 8; ++i) {
        a[i] += __shfl_xor(a[i], 8);
        a[i] += __shfl_xor(a[i], 16);
    }

    float id = invdeg[node];
    uint4 uz = zy4[(size_t)node * 16 + l];
    float v[8];
    v[0] = bflo(uz.x) + a[0] * id; v[1] = bfhi(uz.x) + a[1] * id;
    v[2] = bflo(uz.y) + a[2] * id; v[3] = bfhi(uz.y) + a[3] * id;
    v[4] = bflo(uz.z) + a[4] * id; v[5] = bfhi(uz.z) + a[5] * id;
    v[6] = bflo(uz.w) + a[6] * id; v[7] = bfhi(uz.w) + a[7] * id;

    float m = v[0];
    #pragma unroll
    for (int i = 1; i < 8; ++i) m = fmaxf(m, v[i]);
    #pragma unroll
    for (int msk = 1; msk <= 4; msk <<= 1) m = fmaxf(m, __shfl_xor(m, msk));
    float s = 0.0f;
    #pragma unroll
    for (int i = 0; i < 8; ++i) s += __expf(v[i] - m);
    #pragma unroll
    for (int msk = 1; msk <= 4; msk <<= 1) s += __shfl_xor(s, msk);
    if (sub == 0) {
        float L = m + logf(s);
        float4 o0, o1;
        o0.x = v[0] - L; o0.y = v[1] - L; o0.z = v[2] - L; o0.w = v[3] - L;
        o1.x = v[4] - L; o1.y = v[5] - L; o1.z = v[6] - L; o1.w = v[7] - L;
        ((float4*)out)[(size_t)node * 16 + l * 2] = o0;
        ((float4*)out)[(size_t)node * 16 + l * 2 + 1] = o1;
    }
}

extern "C" void kernel_launch(void* const* d_in, const int* in_sizes, int n_in,
                              void* d_out, int out_size, void* d_ws, size_t ws_size,
                              hipStream_t stream) {
    const float* x   = (const float*)d_in[0];
    const int* esrc  = (const int*)d_in[1];
    const int* edst  = (const int*)d_in[2];
    const float* Wr0 = (const float*)d_in[3];
    const float* Wn0 = (const float*)d_in[4];
    const float* b0  = (const float*)d_in[5];
    const float* g0  = (const float*)d_in[6];
    const float* be0 = (const float*)d_in[7];
    const float* Wr1 = (const float*)d_in[8];
    const float* Wn1 = (const float*)d_in[9];
    const float* b1  = (const float*)d_in[10];
    const float* g1  = (const float*)d_in[11];
    const float* be1 = (const float*)d_in[12];
    const float* Wr2 = (const float*)d_in[13];
    const float* Wn2 = (const float*)d_in[14];
    const float* b2  = (const float*)d_in[15];
    float* out = (float*)d_out;

    char* p = (char*)d_ws;
    auto alloc = [&](size_t bytes) {
        void* r = (void*)p;
        p += (bytes + 255) & ~(size_t)255;
        return r;
    };
    int*   deg    = (int*)  alloc(N_NODES * 4);
    float* invdeg = (float*)alloc(N_NODES * 4);
    int*   rowptr = (int*)  alloc(N_NODES * 4);
    int*   cntG   = (int*)  alloc(NRC * 4);
    int*   bsrc   = (int*)  alloc((size_t)N_EDGES * 4);
    int*   bdst   = (int*)  alloc((size_t)N_EDGES * 4);
    int*   eidx   = (int*)  alloc((size_t)N_EDGES * 4);
    unsigned short* xb   = (unsigned short*)alloc((size_t)NPAD * 128 * 2); // also h2
    unsigned short* h1   = (unsigned short*)alloc((size_t)NPAD * 128 * 2); // also zy
    unsigned short* aggb = (unsigned short*)alloc((size_t)NPAD * 128 * 2);
    unsigned short* WT0  = (unsigned short*)alloc(128 * 256 * 2);
    unsigned short* WT1  = (unsigned short*)alloc(128 * 256 * 2);
    unsigned short* WT2  = (unsigned short*)alloc(128 * 128 * 2);

    // prep (cast + dst-range count) and weight transpose
    k_prep<<<12500 + NC, 256, 0, stream>>>(x, xb, edst, cntG);
    k_prepw_all<<<320, 256, 0, stream>>>(Wr0, Wn0, Wr1, Wn1, Wr2, Wn2, WT0, WT1, WT2);

    // CSR build
    k_scanA<<<1, 256, 0, stream>>>(cntG);
    k_bin<<<NC, 256, 0, stream>>>(esrc, edst, cntG, bsrc, bdst);
    k_nodeplace<<<NR, 256, 0, stream>>>(bsrc, bdst, cntG, deg, invdeg, rowptr, eidx);

    // layer 0
    k_gather<<<N_NODES / 4, 256, 0, stream>>>((const uint4*)xb, eidx, rowptr, deg, invdeg, (uint4*)aggb);
    k_gemm_ln<<<NPAD / 64, 512, 0, stream>>>(xb, aggb, WT0, b0, g0, be0, h1);

    // layer 1 (h2 goes back into xb's buffer)
    k_gather<<<N_NODES / 4, 256, 0, stream>>>((const uint4*)h1, eidx, rowptr, deg, invdeg, (uint4*)aggb);
    k_gemm_ln<<<NPAD / 64, 512, 0, stream>>>(h1, aggb, WT1, b1, g1, be1, xb);

    // layer 2: zy = h2 @ [Wr2|Wn2] (+b2), then gather y-half + log_softmax
    k_gemm2<<<NPAD / 64, 512, 0, stream>>>(xb, WT2, b2, h1);
    k_l2g<<<N_NODES / 8, 256, 0, stream>>>((const uint4*)h1, eidx, rowptr, deg, invdeg, out);
}

// Round 9
// 417.188 us; speedup vs baseline: 1.1846x; 1.0384x over previous
//
#include <hip/hip_runtime.h>
#include <math.h>

#define N_NODES 100000
#define NPAD 100032         // 1563 * 64, padded row count for 64-row GEMM tiles
#define N_EDGES 1600000
#define EPS 1e-5f
#define NC 256              // edge chunks
#define CHUNK 6250          // N_EDGES / NC
#define NR 98               // ceil(100000/1024) dst ranges
#define RSZ 1024            // nodes per range
#define NRC (NR * NC)       // 25088

typedef __bf16 bf16x8 __attribute__((ext_vector_type(8)));
typedef float f32x4 __attribute__((ext_vector_type(4)));
typedef float f32x2 __attribute__((ext_vector_type(2)));

__device__ inline unsigned short f2bf(float f) {    // RNE, finite inputs
    unsigned u = __float_as_uint(f);
    unsigned r = u + 0x7fffu + ((u >> 16) & 1u);
    return (unsigned short)(r >> 16);
}
__device__ inline float bflo(unsigned u) { return __uint_as_float(u << 16); }
__device__ inline float bfhi(unsigned u) { return __uint_as_float(u & 0xffff0000u); }
__device__ inline unsigned pack2(float lo, float hi) {
    return (unsigned)f2bf(lo) | ((unsigned)f2bf(hi) << 16);
}
__device__ inline unsigned char f2fp8(float f) {    // e4m3 via HW cvt
    return (unsigned char)(__builtin_amdgcn_cvt_pk_fp8_f32(f, f, 0, false) & 0xff);
}

// ============ fused prep: x->bf16+fp8 cast (blocks 0..12499) + dst-range
// histogram (blocks 12500..12755) ============
__global__ __launch_bounds__(256) void k_prep(const float* __restrict__ x,
                                              unsigned short* __restrict__ xb,
                                              unsigned* __restrict__ xq8,
                                              const int* __restrict__ dst,
                                              int* __restrict__ cntG) {
    __shared__ int hist[NR];
    int t = threadIdx.x;
    if (blockIdx.x < 12500) {
        int idx = blockIdx.x * 256 + t;     // < N_NODES*32 float4
        float4 v = ((const float4*)x)[idx];
        ushort4 o;
        o.x = f2bf(v.x); o.y = f2bf(v.y); o.z = f2bf(v.z); o.w = f2bf(v.w);
        ((ushort4*)xb)[idx] = o;
        int q = __builtin_amdgcn_cvt_pk_fp8_f32(v.x, v.y, 0, false);
        q = __builtin_amdgcn_cvt_pk_fp8_f32(v.z, v.w, q, true);
        xq8[idx] = (unsigned)q;
    } else {
        int c = blockIdx.x - 12500;
        for (int i = t; i < NR; i += 256) hist[i] = 0;
        __syncthreads();
        int base = c * CHUNK;
        for (int i = base + t; i < base + CHUNK; i += 256)
            atomicAdd(&hist[dst[i] >> 10], 1);
        __syncthreads();
        for (int i = t; i < NR; i += 256) cntG[i * NC + c] = hist[i];
    }
}

// ============ fused: exclusive scan of cntG (block 0) + weight prep
// (blocks 1..320) ============
__global__ __launch_bounds__(256) void k_scanA_prepw(
        int* __restrict__ cntG,
        const float* __restrict__ Wr0, const float* __restrict__ Wn0,
        const float* __restrict__ Wr1, const float* __restrict__ Wn1,
        const float* __restrict__ Wr2, const float* __restrict__ Wn2,
        unsigned short* __restrict__ WT0, unsigned short* __restrict__ WT1,
        unsigned short* __restrict__ WT2) {
    int t = threadIdx.x;
    if (blockIdx.x == 0) {
        __shared__ int ts[256];
        const int PER = NRC / 256;          // 98
        int s = 0;
        for (int i = 0; i < PER; ++i) s += cntG[t * PER + i];
        ts[t] = s;
        __syncthreads();
        #pragma unroll
        for (int off = 1; off < 256; off <<= 1) {
            int y = 0;
            if (t >= off) y = ts[t - off];
            __syncthreads();
            if (t >= off) ts[t] += y;
            __syncthreads();
        }
        int run = ts[t] - s;                // exclusive
        for (int i = 0; i < PER; ++i) {
            int v = cntG[t * PER + i];
            cntG[t * PER + i] = run;
            run += v;
        }
    } else {
        int b = blockIdx.x - 1;
        if (b < 256) {
            const float* Wr = (b < 128) ? Wr0 : Wr1;
            const float* Wn = (b < 128) ? Wn0 : Wn1;
            unsigned short* WT = (b < 128) ? WT0 : WT1;
            int idx = (b & 127) * 256 + t;
            int n = idx >> 8;
            int kc = idx & 255;
            float v = (kc < 128) ? Wr[kc * 128 + n] : Wn[(kc - 128) * 128 + n];
            WT[idx] = f2bf(v);
        } else {
            int idx = (b - 256) * 256 + t;  // < 128*128
            int n = idx >> 7;
            int k = idx & 127;
            float v = (n < 64) ? Wr2[k * 64 + n] : Wn2[k * 64 + (n - 64)];
            WT2[n * 128 + k] = f2bf(v);
        }
    }
}

// ============ bin edges by dst-range; packed (src<<10 | dstlocal) ============
__global__ __launch_bounds__(256) void k_bin(const int* __restrict__ src,
                                             const int* __restrict__ dst,
                                             const int* __restrict__ baseG,
                                             unsigned* __restrict__ bpack) {
    __shared__ int cur[NR];
    int t = threadIdx.x, c = blockIdx.x;
    for (int i = t; i < NR; i += 256) cur[i] = baseG[i * NC + c];
    __syncthreads();
    int base = c * CHUNK;
    for (int i = base + t; i < base + CHUNK; i += 256) {
        int d = dst[i];
        unsigned s = (unsigned)src[i];
        int p = atomicAdd(&cur[d >> 10], 1);
        bpack[p] = (s << 10) | (unsigned)(d & 1023);
    }
}

// ============ fused per-range: histogram -> deg/invdeg/rowptr -> place =====
__global__ __launch_bounds__(256) void k_nodeplace(
        const unsigned* __restrict__ bpack, const int* __restrict__ baseG,
        int* __restrict__ deg, float* __restrict__ invdeg,
        int* __restrict__ rowptr, int* __restrict__ eidx) {
    __shared__ int hist[RSZ];
    __shared__ int cur[RSZ];
    __shared__ int ps[256];
    int r = blockIdx.x, t = threadIdx.x;
    for (int i = t; i < RSZ; i += 256) hist[i] = 0;
    __syncthreads();
    int s0 = baseG[r * NC];
    int s1 = (r == NR - 1) ? N_EDGES : baseG[(r + 1) * NC];
    int nbase = r << 10;
    for (int i = s0 + t; i < s1; i += 256)
        atomicAdd(&hist[bpack[i] & 1023u], 1);
    __syncthreads();
    int h0 = hist[4 * t], h1 = hist[4 * t + 1], h2 = hist[4 * t + 2], h3 = hist[4 * t + 3];
    int tsum = h0 + h1 + h2 + h3;
    ps[t] = tsum;
    __syncthreads();
    #pragma unroll
    for (int off = 1; off < 256; off <<= 1) {
        int y = 0;
        if (t >= off) y = ps[t - off];
        __syncthreads();
        if (t >= off) ps[t] += y;
        __syncthreads();
    }
    int p = s0 + ps[t] - tsum;
    int n = nbase + 4 * t;
    int d[4] = {h0, h1, h2, h3};
    #pragma unroll
    for (int k = 0; k < 4; ++k) {
        cur[4 * t + k] = p;
        if (n + k < N_NODES) {
            rowptr[n + k] = p;
            deg[n + k] = d[k];
            invdeg[n + k] = 1.0f / fmaxf((float)d[k], 1.0f);
        }
        p += d[k];
    }
    __syncthreads();
    for (int i = s0 + t; i < s1; i += 256) {
        unsigned bp = bpack[i];
        int pp = atomicAdd(&cur[bp & 1023u], 1);
        eidx[pp] = (int)(bp >> 10);
    }
}

// ---------------- gather mean-aggregation (fp8 in, bf16 out, 128-dim) ------
// One wave per node; fp8 row = 128B = 8 lanes x uint4; sub = lane>>3 picks
// the edge -> 8 edge rows per wave-wide load. Packed f32x2 accumulate
// (v_pk_add_f32). Reduce xor 8,16,32; lanes 0-7 write 32B bf16 each.
__global__ __launch_bounds__(256) void k_gather(const uint4* __restrict__ hq4,
                                                const int* __restrict__ eidx,
                                                const int* __restrict__ rowptr,
                                                const int* __restrict__ deg,
                                                const float* __restrict__ invdeg,
                                                uint4* __restrict__ aggw4) {
    int node = blockIdx.x * 4 + (threadIdx.x >> 6);
    int lane = threadIdx.x & 63;
    int sub = lane >> 3;       // edge subgroup 0..7
    int l = lane & 7;          // 16B chunk of the 128B fp8 row
    int start = rowptr[node];
    int cnt = deg[node];
    f32x2 a[8];
    #pragma unroll
    for (int i = 0; i < 8; ++i) a[i] = (f32x2)0.0f;

    auto accum = [&](uint4 u) {
        a[0] += __builtin_amdgcn_cvt_pk_f32_fp8((int)u.x, false);
        a[1] += __builtin_amdgcn_cvt_pk_f32_fp8((int)u.x, true);
        a[2] += __builtin_amdgcn_cvt_pk_f32_fp8((int)u.y, false);
        a[3] += __builtin_amdgcn_cvt_pk_f32_fp8((int)u.y, true);
        a[4] += __builtin_amdgcn_cvt_pk_f32_fp8((int)u.z, false);
        a[5] += __builtin_amdgcn_cvt_pk_f32_fp8((int)u.z, true);
        a[6] += __builtin_amdgcn_cvt_pk_f32_fp8((int)u.w, false);
        a[7] += __builtin_amdgcn_cvt_pk_f32_fp8((int)u.w, true);
    };

    int j = 0;
    for (; j + 16 <= cnt; j += 16) {
        int s0 = eidx[start + j + sub];
        int s1 = eidx[start + j + 8 + sub];
        uint4 u0 = hq4[(size_t)s0 * 8 + l];
        uint4 u1 = hq4[(size_t)s1 * 8 + l];
        accum(u0);
        accum(u1);
    }
    if (j + 8 <= cnt) {
        uint4 u0 = hq4[(size_t)eidx[start + j + sub] * 8 + l];
        accum(u0);
        j += 8;
    }
    int rem = cnt - j;          // 0..7
    if (sub < rem) {
        uint4 u0 = hq4[(size_t)eidx[start + j + sub] * 8 + l];
        accum(u0);
    }
    #pragma unroll
    for (int i = 0; i < 8; ++i) {
        a[i].x += __shfl_xor(a[i].x, 8);  a[i].y += __shfl_xor(a[i].y, 8);
        a[i].x += __shfl_xor(a[i].x, 16); a[i].y += __shfl_xor(a[i].y, 16);
        a[i].x += __shfl_xor(a[i].x, 32); a[i].y += __shfl_xor(a[i].y, 32);
    }
    if (sub == 0) {
        float id = invdeg[node];
        uint4 o0, o1;
        o0.x = pack2(a[0].x * id, a[0].y * id);
        o0.y = pack2(a[1].x * id, a[1].y * id);
        o0.z = pack2(a[2].x * id, a[2].y * id);
        o0.w = pack2(a[3].x * id, a[3].y * id);
        o1.x = pack2(a[4].x * id, a[4].y * id);
        o1.y = pack2(a[5].x * id, a[5].y * id);
        o1.z = pack2(a[6].x * id, a[6].y * id);
        o1.w = pack2(a[7].x * id, a[7].y * id);
        aggw4[(size_t)node * 16 + l * 2] = o0;
        aggw4[(size_t)node * 16 + l * 2 + 1] = o1;
    }
}

// ------ MFMA dual-GEMM + bias + LayerNorm + ReLU (K=256 -> 128), 64 rows ---
// Optional fp8 shadow copy of the output (for the next layer's gather).
__global__ __launch_bounds__(512) void k_gemm_ln(
        const unsigned short* __restrict__ hb, const unsigned short* __restrict__ ab,
        const unsigned short* __restrict__ WT,
        const float* __restrict__ b, const float* __restrict__ g,
        const float* __restrict__ be, unsigned short* __restrict__ outb,
        unsigned char* __restrict__ outq8) {
    __shared__ unsigned short hl[64][136];
    __shared__ unsigned short al[64][136];
    __shared__ unsigned short bt[128][72];
    __shared__ float p1[2][64], p2[2][64];

    const int tid = threadIdx.x;
    const int lane = tid & 63;
    const int w = tid >> 6;
    const int quad = lane >> 4;
    const int l15 = lane & 15;
    const int rt = w >> 1;
    const int ch = w & 1;
    const int row0 = blockIdx.x * 64;

    #pragma unroll
    for (int t = 0; t < 2; ++t) {
        int idx = tid + t * 512;
        int r = idx >> 4;
        int c8 = idx & 15;
        *(float4*)&hl[r][c8 * 8] = ((const float4*)hb)[(size_t)(row0 + r) * 16 + c8];
        *(float4*)&al[r][c8 * 8] = ((const float4*)ab)[(size_t)(row0 + r) * 16 + c8];
    }

    f32x4 acc[4];
    #pragma unroll
    for (int t = 0; t < 4; ++t)
        #pragma unroll
        for (int r = 0; r < 4; ++r) acc[t][r] = 0.0f;

    #pragma unroll
    for (int kt = 0; kt < 4; ++kt) {
        __syncthreads();
        #pragma unroll
        for (int t = 0; t < 2; ++t) {
            int idx = tid + t * 512;
            int n = idx >> 3;
            int c8 = idx & 7;
            *(float4*)&bt[n][c8 * 8] = ((const float4*)WT)[n * 32 + kt * 8 + c8];
        }
        __syncthreads();
        #pragma unroll
        for (int ks = 0; ks < 2; ++ks) {
            const int ck = kt * 64 + ks * 32;
            const unsigned short* ap = (ck < 128)
                ? &hl[rt * 16 + l15][ck + quad * 8]
                : &al[rt * 16 + l15][ck - 128 + quad * 8];
            bf16x8 a = *(const bf16x8*)ap;
            #pragma unroll
            for (int t = 0; t < 4; ++t) {
                bf16x8 bb = *(const bf16x8*)&bt[ch * 64 + t * 16 + l15][ks * 32 + quad * 8];
                acc[t] = __builtin_amdgcn_mfma_f32_16x16x32_bf16(a, bb, acc[t], 0, 0, 0);
            }
        }
    }

    float bcol[4], gc[4], bec[4];
    #pragma unroll
    for (int t = 0; t < 4; ++t) {
        int col = ch * 64 + t * 16 + l15;
        bcol[t] = b[col]; gc[t] = g[col]; bec[t] = be[col];
    }
    float v[4][4];
    float s1[4], s2[4];
    #pragma unroll
    for (int r = 0; r < 4; ++r) { s1[r] = 0.0f; s2[r] = 0.0f; }
    #pragma unroll
    for (int t = 0; t < 4; ++t)
        #pragma unroll
        for (int r = 0; r < 4; ++r) {
            float x = acc[t][r] + bcol[t];
            v[t][r] = x;
            s1[r] += x;
            s2[r] += x * x;
        }
    #pragma unroll
    for (int m = 1; m <= 8; m <<= 1)
        #pragma unroll
        for (int r = 0; r < 4; ++r) {
            s1[r] += __shfl_xor(s1[r], m);
            s2[r] += __shfl_xor(s2[r], m);
        }
    if (l15 == 0) {
        #pragma unroll
        for (int r = 0; r < 4; ++r) {
            int rl = rt * 16 + quad * 4 + r;
            p1[ch][rl] = s1[r];
            p2[ch][rl] = s2[r];
        }
    }
    __syncthreads();
    #pragma unroll
    for (int r = 0; r < 4; ++r) {
        int rl = rt * 16 + quad * 4 + r;
        float S1 = p1[0][rl] + p1[1][rl];
        float S2 = p2[0][rl] + p2[1][rl];
        float mean = S1 * (1.0f / 128.0f);
        float var = S2 * (1.0f / 128.0f) - mean * mean;
        float rstd = rsqrtf(var + EPS);
        #pragma unroll
        for (int t = 0; t < 4; ++t) {
            int col = ch * 64 + t * 16 + l15;
            float o = fmaxf((v[t][r] - mean) * rstd * gc[t] + bec[t], 0.0f);
            outb[(size_t)(row0 + rl) * 128 + col] = f2bf(o);
            if (outq8) outq8[(size_t)(row0 + rl) * 128 + col] = f2fp8(o);
        }
    }
}

// ------ layer 2 GEMM: z(+b2) -> bf16, y -> fp8 shadow, 64 rows -------------
__global__ __launch_bounds__(512) void k_gemm2(
        const unsigned short* __restrict__ hb, const unsigned short* __restrict__ WT,
        const float* __restrict__ b2, unsigned short* __restrict__ zb16,
        unsigned char* __restrict__ yq8) {
    __shared__ unsigned short hl[64][136];
    __shared__ unsigned short bt[128][136];

    const int tid = threadIdx.x;
    const int lane = tid & 63;
    const int w = tid >> 6;
    const int quad = lane >> 4;
    const int l15 = lane & 15;
    const int rt = w >> 1;
    const int ch = w & 1;
    const int row0 = blockIdx.x * 64;

    #pragma unroll
    for (int t = 0; t < 2; ++t) {
        int idx = tid + t * 512;
        int r = idx >> 4;
        int c8 = idx & 15;
        *(float4*)&hl[r][c8 * 8] = ((const float4*)hb)[(size_t)(row0 + r) * 16 + c8];
    }
    #pragma unroll
    for (int t = 0; t < 4; ++t) {
        int idx = tid + t * 512;
        int n = idx >> 4;
        int c8 = idx & 15;
        *(float4*)&bt[n][c8 * 8] = ((const float4*)WT)[n * 16 + c8];
    }
    __syncthreads();

    f32x4 acc[4];
    #pragma unroll
    for (int t = 0; t < 4; ++t)
        #pragma unroll
        for (int r = 0; r < 4; ++r) acc[t][r] = 0.0f;

    #pragma unroll
    for (int ks = 0; ks < 4; ++ks) {
        bf16x8 a = *(const bf16x8*)&hl[rt * 16 + l15][ks * 32 + quad * 8];
        #pragma unroll
        for (int t = 0; t < 4; ++t) {
            bf16x8 bb = *(const bf16x8*)&bt[ch * 64 + t * 16 + l15][ks * 32 + quad * 8];
            acc[t] = __builtin_amdgcn_mfma_f32_16x16x32_bf16(a, bb, acc[t], 0, 0, 0);
        }
    }

    if (ch == 0) {      // z half: cols 0..63, + bias, bf16
        #pragma unroll
        for (int t = 0; t < 4; ++t) {
            int col = t * 16 + l15;
            float bc = b2[col];
            #pragma unroll
            for (int r = 0; r < 4; ++r) {
                int rl = rt * 16 + quad * 4 + r;
                zb16[(size_t)(row0 + rl) * 64 + col] = f2bf(acc[t][r] + bc);
            }
        }
    } else {            // y half: cols 0..63 of y, fp8
        #pragma unroll
        for (int t = 0; t < 4; ++t) {
            int col = t * 16 + l15;
            #pragma unroll
            for (int r = 0; r < 4; ++r) {
                int rl = rt * 16 + quad * 4 + r;
                yq8[(size_t)(row0 + rl) * 64 + col] = f2fp8(acc[t][r]);
            }
        }
    }
}

// ------- final: gather-mean y (fp8, 64-dim) + z + log_softmax, fp32 out ----
// 32-lane group per node; y row = 64B = 4 lanes x uint4; sub = lane>>2 picks
// the edge (8 edges per 32-lane load). Reduce xor 4,8,16; lanes 0-3 epilogue.
__global__ __launch_bounds__(256) void k_l2g(const uint4* __restrict__ yq4,
                                             const unsigned short* __restrict__ zb16,
                                             const int* __restrict__ eidx,
                                             const int* __restrict__ rowptr,
                                             const int* __restrict__ deg,
                                             const float* __restrict__ invdeg,
                                             float* __restrict__ out) {
    int node = blockIdx.x * 8 + (threadIdx.x >> 5);
    int lane = threadIdx.x & 31;
    int sub = lane >> 2;       // edge subgroup 0..7
    int l = lane & 3;          // 16B chunk of the 64B fp8 y row
    int start = rowptr[node];
    int cnt = deg[node];
    f32x2 a[8];
    #pragma unroll
    for (int i = 0; i < 8; ++i) a[i] = (f32x2)0.0f;

    auto accum = [&](uint4 u) {
        a[0] += __builtin_amdgcn_cvt_pk_f32_fp8((int)u.x, false);
        a[1] += __builtin_amdgcn_cvt_pk_f32_fp8((int)u.x, true);
        a[2] += __builtin_amdgcn_cvt_pk_f32_fp8((int)u.y, false);
        a[3] += __builtin_amdgcn_cvt_pk_f32_fp8((int)u.y, true);
        a[4] += __builtin_amdgcn_cvt_pk_f32_fp8((int)u.z, false);
        a[5] += __builtin_amdgcn_cvt_pk_f32_fp8((int)u.z, true);
        a[6] += __builtin_amdgcn_cvt_pk_f32_fp8((int)u.w, false);
        a[7] += __builtin_amdgcn_cvt_pk_f32_fp8((int)u.w, true);
    };

    int j = 0;
    for (; j + 16 <= cnt; j += 16) {
        int s0 = eidx[start + j + sub];
        int s1 = eidx[start + j + 8 + sub];
        uint4 u0 = yq4[(size_t)s0 * 4 + l];
        uint4 u1 = yq4[(size_t)s1 * 4 + l];
        accum(u0);
        accum(u1);
    }
    if (j + 8 <= cnt) {
        uint4 u0 = yq4[(size_t)eidx[start + j + sub] * 4 + l];
        accum(u0);
        j += 8;
    }
    int rem = cnt - j;
    if (sub < rem) {
        uint4 u0 = yq4[(size_t)eidx[start + j + sub] * 4 + l];
        accum(u0);
    }
    #pragma unroll
    for (int i = 0; i < 8; ++i) {
        a[i].x += __shfl_xor(a[i].x, 4);  a[i].y += __shfl_xor(a[i].y, 4);
        a[i].x += __shfl_xor(a[i].x, 8);  a[i].y += __shfl_xor(a[i].y, 8);
        a[i].x += __shfl_xor(a[i].x, 16); a[i].y += __shfl_xor(a[i].y, 16);
    }

    // all lanes: v = z + mean(y) for cols 16l..16l+15
    float id = invdeg[node];
    uint4 z0 = ((const uint4*)zb16)[(size_t)node * 8 + l * 2];
    uint4 z1 = ((const uint4*)zb16)[(size_t)node * 8 + l * 2 + 1];
    float v[16];
    v[0]  = bflo(z0.x) + a[0].x * id; v[1]  = bfhi(z0.x) + a[0].y * id;
    v[2]  = bflo(z0.y) + a[1].x * id; v[3]  = bfhi(z0.y) + a[1].y * id;
    v[4]  = bflo(z0.z) + a[2].x * id; v[5]  = bfhi(z0.z) + a[2].y * id;
    v[6]  = bflo(z0.w) + a[3].x * id; v[7]  = bfhi(z0.w) + a[3].y * id;
    v[8]  = bflo(z1.x) + a[4].x * id; v[9]  = bfhi(z1.x) + a[4].y * id;
    v[10] = bflo(z1.y) + a[5].x * id; v[11] = bfhi(z1.y) + a[5].y * id;
    v[12] = bflo(z1.z) + a[6].x * id; v[13] = bfhi(z1.z) + a[6].y * id;
    v[14] = bflo(z1.w) + a[7].x * id; v[15] = bfhi(z1.w) + a[7].y * id;

    float m = v[0];
    #pragma unroll
    for (int i = 1; i < 16; ++i) m = fmaxf(m, v[i]);
    m = fmaxf(m, __shfl_xor(m, 1));
    m = fmaxf(m, __shfl_xor(m, 2));
    float s = 0.0f;
    #pragma unroll
    for (int i = 0; i < 16; ++i) s += __expf(v[i] - m);
    s += __shfl_xor(s, 1);
    s += __shfl_xor(s, 2);
    if (sub == 0) {
        float L = m + logf(s);
        #pragma unroll
        for (int k = 0; k < 4; ++k) {
            float4 o;
            o.x = v[4 * k] - L; o.y = v[4 * k + 1] - L;
            o.z = v[4 * k + 2] - L; o.w = v[4 * k + 3] - L;
            ((float4*)out)[(size_t)node * 16 + l * 4 + k] = o;
        }
    }
}

extern "C" void kernel_launch(void* const* d_in, const int* in_sizes, int n_in,
                              void* d_out, int out_size, void* d_ws, size_t ws_size,
                              hipStream_t stream) {
    const float* x   = (const float*)d_in[0];
    const int* esrc  = (const int*)d_in[1];
    const int* edst  = (const int*)d_in[2];
    const float* Wr0 = (const float*)d_in[3];
    const float* Wn0 = (const float*)d_in[4];
    const float* b0  = (const float*)d_in[5];
    const float* g0  = (const float*)d_in[6];
    const float* be0 = (const float*)d_in[7];
    const float* Wr1 = (const float*)d_in[8];
    const float* Wn1 = (const float*)d_in[9];
    const float* b1  = (const float*)d_in[10];
    const float* g1  = (const float*)d_in[11];
    const float* be1 = (const float*)d_in[12];
    const float* Wr2 = (const float*)d_in[13];
    const float* Wn2 = (const float*)d_in[14];
    const float* b2  = (const float*)d_in[15];
    float* out = (float*)d_out;

    char* p = (char*)d_ws;
    auto alloc = [&](size_t bytes) {
        void* r = (void*)p;
        p += (bytes + 255) & ~(size_t)255;
        return r;
    };
    int*   deg    = (int*)  alloc(N_NODES * 4);
    float* invdeg = (float*)alloc(N_NODES * 4);
    int*   rowptr = (int*)  alloc(N_NODES * 4);
    int*   cntG   = (int*)  alloc(NRC * 4);
    unsigned* bpack = (unsigned*)alloc((size_t)N_EDGES * 4);
    int*   eidx   = (int*)  alloc((size_t)N_EDGES * 4);
    unsigned short* xb   = (unsigned short*)alloc((size_t)NPAD * 128 * 2); // also h2
    unsigned short* h1   = (unsigned short*)alloc((size_t)NPAD * 128 * 2);
    unsigned short* aggb = (unsigned short*)alloc((size_t)NPAD * 128 * 2);
    unsigned*       xq8  = (unsigned*)      alloc((size_t)N_NODES * 128);
    unsigned char*  h1q8 = (unsigned char*) alloc((size_t)NPAD * 128);
    unsigned short* zb16 = (unsigned short*)alloc((size_t)NPAD * 64 * 2);
    unsigned char*  yq8  = (unsigned char*) alloc((size_t)NPAD * 64);
    unsigned short* WT0  = (unsigned short*)alloc(128 * 256 * 2);
    unsigned short* WT1  = (unsigned short*)alloc(128 * 256 * 2);
    unsigned short* WT2  = (unsigned short*)alloc(128 * 128 * 2);

    // prep (cast bf16+fp8 + dst-range count); scan + weight transpose
    k_prep<<<12500 + NC, 256, 0, stream>>>(x, xb, xq8, edst, cntG);
    k_scanA_prepw<<<321, 256, 0, stream>>>(cntG, Wr0, Wn0, Wr1, Wn1, Wr2, Wn2,
                                           WT0, WT1, WT2);
    k_bin<<<NC, 256, 0, stream>>>(esrc, edst, cntG, bpack);
    k_nodeplace<<<NR, 256, 0, stream>>>(bpack, cntG, deg, invdeg, rowptr, eidx);

    // layer 0
    k_gather<<<N_NODES / 4, 256, 0, stream>>>((const uint4*)xq8, eidx, rowptr, deg, invdeg, (uint4*)aggb);
    k_gemm_ln<<<NPAD / 64, 512, 0, stream>>>(xb, aggb, WT0, b0, g0, be0, h1, h1q8);

    // layer 1 (h2 goes back into xb's buffer; no fp8 copy needed)
    k_gather<<<N_NODES / 4, 256, 0, stream>>>((const uint4*)h1q8, eidx, rowptr, deg, invdeg, (uint4*)aggb);
    k_gemm_ln<<<NPAD / 64, 512, 0, stream>>>(h1, aggb, WT1, b1, g1, be1, xb, (unsigned char*)nullptr);

    // layer 2: z (bf16) + y (fp8), then gather y + log_softmax
    k_gemm2<<<NPAD / 64, 512, 0, stream>>>(xb, WT2, b2, zb16, yq8);
    k_l2g<<<N_NODES / 8, 256, 0, stream>>>((const uint4*)yq8, zb16, eidx, rowptr, deg, invdeg, out);
}